// Round 1
// baseline (171.679 us; speedup 1.0000x reference)
//
#include <hip/hip_runtime.h>
#include <stdint.h>

#define VOCAB   100000
#define DIM     300
#define NBATCH  4096
#define RTOK    32
#define NSUP    64      // N*S = 2*32 support cols
#define KP      320     // K padded to 10*32
#define NKS     10      // K steps of 32
#define ASTRIDE 328     // LDS row stride (ushort) for A tiles
#define SMST    65      // LDS row stride (float) for sm tile

typedef float f32x4 __attribute__((ext_vector_type(4)));
typedef short s16x8 __attribute__((ext_vector_type(8)));

static __device__ __forceinline__ unsigned short f2bf(float x) {
    unsigned u = __builtin_bit_cast(unsigned, x);
    unsigned r = (u + 0x7FFFu + ((u >> 16) & 1u)) >> 16;
    return (unsigned short)r;
}
static __device__ __forceinline__ float bf2f(unsigned short h) {
    return __builtin_bit_cast(float, (unsigned)h << 16);
}

// ---------------- kernel 1: normalize support vectors -> bf16 hi/lo [64][320]
__global__ __launch_bounds__(256) void prep_kernel(
    const int* __restrict__ sidx, const float* __restrict__ emb,
    unsigned short* __restrict__ Bh, unsigned short* __restrict__ Bl) {
    const int w = threadIdx.x >> 6, l = threadIdx.x & 63;
    for (int rr = 0; rr < 16; ++rr) {
        const int j = w * 16 + rr;
        const size_t tok = (size_t)sidx[j];
        const float* src = emb + tok * DIM;
        float e[5];
        #pragma unroll
        for (int c = 0; c < 5; ++c) {
            const int k = c * 64 + l;
            e[c] = (k < DIM) ? src[k] : 0.f;
        }
        float s = e[0]*e[0] + e[1]*e[1] + e[2]*e[2] + e[3]*e[3] + e[4]*e[4];
        #pragma unroll
        for (int m = 32; m >= 1; m >>= 1) s += __shfl_xor(s, m);
        const float rn = 1.f / fmaxf(sqrtf(s), 1e-8f);
        #pragma unroll
        for (int c = 0; c < 5; ++c) {
            const int k = c * 64 + l;                 // always < 320
            const float v = (k < DIM) ? e[c] * rn : 0.f;
            const unsigned short h = f2bf(v);
            Bh[j * KP + k] = h;
            Bl[j * KP + k] = f2bf(v - bf2f(h));
        }
    }
}

// ---------------- kernel 2: fused gather+normalize+GEMM(split-bf16 MFMA)+tail
__global__ __launch_bounds__(512) void main_kernel(
    const int* __restrict__ tokens, const float* __restrict__ emb,
    const unsigned short* __restrict__ Bh, const unsigned short* __restrict__ Bl,
    const float* __restrict__ c1w, const float* __restrict__ c1b,
    const float* __restrict__ c2w, const float* __restrict__ c2b,
    const float* __restrict__ f2w, const float* __restrict__ f2b,
    const float* __restrict__ fcw, const float* __restrict__ fcb,
    float* __restrict__ out) {

    __shared__ __attribute__((aligned(16))) unsigned short Ah[32 * ASTRIDE];
    __shared__ __attribute__((aligned(16))) unsigned short Al[32 * ASTRIDE];
    __shared__ float smls[32 * SMST];
    __shared__ float pl1[2 * 16 * 16];
    __shared__ float scr[32];

    const int tid = threadIdx.x;
    const int w = tid >> 6, l = tid & 63;

    // B fragments: loaded once per block, reused for 8 batches.
    // lane l of wave w holds B[k=(l>>4)*8 + i][col=(w&3)*16 + (l&15)] per k-step
    const int cb = (w & 3) * 16;
    s16x8 rbh[NKS], rbl[NKS];
    #pragma unroll
    for (int t = 0; t < NKS; ++t) {
        const int off = (cb + (l & 15)) * KP + t * 32 + (l >> 4) * 8;
        rbh[t] = *(const s16x8*)(Bh + off);
        rbl[t] = *(const s16x8*)(Bl + off);
    }

    for (int it = 0; it < 8; ++it) {
        const int batch = blockIdx.x * 8 + it;

        // ---- gather + normalize + bf16 hi/lo into LDS (wave w: rows 4w..4w+3)
        #pragma unroll
        for (int rr = 0; rr < 4; ++rr) {
            const int row = w * 4 + rr;
            const size_t tok = (size_t)tokens[batch * RTOK + row];
            const float* src = emb + tok * DIM;
            float e[5];
            #pragma unroll
            for (int c = 0; c < 5; ++c) {
                const int k = c * 64 + l;
                e[c] = (k < DIM) ? src[k] : 0.f;
            }
            float s = e[0]*e[0] + e[1]*e[1] + e[2]*e[2] + e[3]*e[3] + e[4]*e[4];
            #pragma unroll
            for (int m = 32; m >= 1; m >>= 1) s += __shfl_xor(s, m);
            const float rn = 1.f / fmaxf(sqrtf(s), 1e-8f);
            #pragma unroll
            for (int c = 0; c < 5; ++c) {
                const int k = c * 64 + l;             // covers 0..319 incl. zero pad
                const float v = (k < DIM) ? e[c] * rn : 0.f;
                const unsigned short h = f2bf(v);
                Ah[row * ASTRIDE + k] = h;
                Al[row * ASTRIDE + k] = f2bf(v - bf2f(h));
            }
        }
        __syncthreads();

        // ---- MFMA: wave w -> rows (w>>2)*16..+15, cols (w&3)*16..+15
        {
            const int rb = (w >> 2) * 16;
            f32x4 a0 = {0,0,0,0}, a1 = {0,0,0,0}, a2 = {0,0,0,0};
            const int abase = (rb + (l & 15)) * ASTRIDE + (l >> 4) * 8;
            #pragma unroll
            for (int t = 0; t < NKS; ++t) {
                const s16x8 ah = *(const s16x8*)(Ah + abase + t * 32);
                const s16x8 al = *(const s16x8*)(Al + abase + t * 32);
                a0 = __builtin_amdgcn_mfma_f32_16x16x32_bf16(ah, rbh[t], a0, 0, 0, 0);
                a1 = __builtin_amdgcn_mfma_f32_16x16x32_bf16(ah, rbl[t], a1, 0, 0, 0);
                a2 = __builtin_amdgcn_mfma_f32_16x16x32_bf16(al, rbh[t], a2, 0, 0, 0);
            }
            #pragma unroll
            for (int q = 0; q < 4; ++q) {
                const int row = rb + (l >> 4) * 4 + q;
                smls[row * SMST + cb + (l & 15)] = a0[q] + a1[q] + a2[q];
            }
        }
        __syncthreads();

        // ---- softmax-pool + gate (all 8 waves; waves 0-3 ch0, 4-7 ch1)
        float g0, g1;
        {
            const int ch = w >> 2;
            const int i0 = (w & 3) * 256 + l * 4;
            float v[4];
            #pragma unroll
            for (int i = 0; i < 4; ++i) {
                const int idx = i0 + i;               // idx = s*32 + r
                v[i] = smls[(idx & 31) * SMST + ch * 32 + (idx >> 5)];
            }
            float m = fmaxf(fmaxf(v[0], v[1]), fmaxf(v[2], v[3]));
            #pragma unroll
            for (int k = 32; k >= 1; k >>= 1) m = fmaxf(m, __shfl_xor(m, k));
            if (l == 0) scr[8 + w] = m;
            __syncthreads();
            m = fmaxf(fmaxf(scr[8 + (ch << 2)], scr[9 + (ch << 2)]),
                      fmaxf(scr[10 + (ch << 2)], scr[11 + (ch << 2)]));
            float se = 0.f, sv = 0.f;
            #pragma unroll
            for (int i = 0; i < 4; ++i) {
                const float e = expf(v[i] - m);
                se += e; sv += e * v[i];
            }
            #pragma unroll
            for (int k = 32; k >= 1; k >>= 1) { se += __shfl_xor(se, k); sv += __shfl_xor(sv, k); }
            if (l == 0) { scr[16 + w] = se; scr[24 + w] = sv; }
            __syncthreads();
            const float p0 = (scr[24]+scr[25]+scr[26]+scr[27]) / (scr[16]+scr[17]+scr[18]+scr[19]);
            const float p1 = (scr[28]+scr[29]+scr[30]+scr[31]) / (scr[20]+scr[21]+scr[22]+scr[23]);
            g0 = 1.f / (1.f + expf(-(f2w[0]*p0 + f2w[1]*p1 + f2b[0])));
            g1 = 1.f / (1.f + expf(-(f2w[2]*p0 + f2w[3]*p1 + f2b[1])));
        }

        // ---- conv1(3x3,pad1)+relu+maxpool2 -> pl1[2][16][16]; 1 output/thread
        {
            const int oc = tid >> 8, ii = (tid >> 4) & 15, jj = tid & 15;
            float mx = 0.f;   // relu'd values are >= 0
            #pragma unroll
            for (int py = 0; py < 2; ++py)
            #pragma unroll
            for (int px = 0; px < 2; ++px) {
                const int y = 2 * ii + py, x = 2 * jj + px;
                float acc = c1b[oc];
                #pragma unroll
                for (int ic = 0; ic < 2; ++ic) {
                    const float g = ic ? g1 : g0;
                    #pragma unroll
                    for (int dy = 0; dy < 3; ++dy) {
                        const int yy = y - 1 + dy;
                        if (yy < 0 || yy > 31) continue;
                        #pragma unroll
                        for (int dx = 0; dx < 3; ++dx) {
                            const int xx = x - 1 + dx;
                            if (xx < 0 || xx > 31) continue;
                            acc += c1w[((oc * 2 + ic) * 3 + dy) * 3 + dx] * g *
                                   smls[xx * SMST + ic * 32 + yy];
                        }
                    }
                }
                mx = fmaxf(mx, fmaxf(acc, 0.f));
            }
            pl1[tid >= 512 ? 0 : tid] = mx;   // tid == oc*256+ii*16+jj
        }
        __syncthreads();

        // ---- conv2(2x2,pad1)+relu+avgpool2 -> [2][8][8] + fc partials
        float c0 = 0.f, c1 = 0.f;
        if (tid < 128) {
            const int oc = tid >> 6, ii = (tid >> 3) & 7, jj = tid & 7;
            float sum = 0.f;
            #pragma unroll
            for (int py = 0; py < 2; ++py)
            #pragma unroll
            for (int px = 0; px < 2; ++px) {
                const int y = 2 * ii + py, x = 2 * jj + px;
                float acc = c2b[oc];
                #pragma unroll
                for (int ic = 0; ic < 2; ++ic)
                #pragma unroll
                for (int dy = 0; dy < 2; ++dy) {
                    const int yy = y - 1 + dy;
                    if (yy < 0 || yy > 15) continue;
                    #pragma unroll
                    for (int dx = 0; dx < 2; ++dx) {
                        const int xx = x - 1 + dx;
                        if (xx < 0 || xx > 15) continue;
                        acc += c2w[((oc * 2 + ic) * 2 + dy) * 2 + dx] *
                               pl1[ic * 256 + yy * 16 + xx];
                    }
                }
                sum += fmaxf(acc, 0.f);
            }
            const float val = 0.25f * sum;        // flat idx == tid
            c0 = val * fcw[tid];
            c1 = val * fcw[128 + tid];
        }
        #pragma unroll
        for (int k = 32; k >= 1; k >>= 1) { c0 += __shfl_xor(c0, k); c1 += __shfl_xor(c1, k); }
        if (l == 0 && w < 2) { scr[w * 2] = c0; scr[w * 2 + 1] = c1; }
        __syncthreads();
        if (tid == 0) {
            out[batch * 2 + 0] = fcb[0] + scr[0] + scr[2];
            out[batch * 2 + 1] = fcb[1] + scr[1] + scr[3];
        }
        __syncthreads();   // protect LDS reuse across iterations
    }
}

extern "C" void kernel_launch(void* const* d_in, const int* in_sizes, int n_in,
                              void* d_out, int out_size, void* d_ws, size_t ws_size,
                              hipStream_t stream) {
    const int* tokens = (const int*)d_in[0];
    const int* sidx   = (const int*)d_in[1];
    const float* emb  = (const float*)d_in[2];
    const float* c1w  = (const float*)d_in[3];
    const float* c1b  = (const float*)d_in[4];
    const float* c2w  = (const float*)d_in[5];
    const float* c2b  = (const float*)d_in[6];
    const float* f2w  = (const float*)d_in[7];
    const float* f2b  = (const float*)d_in[8];
    const float* fcw  = (const float*)d_in[9];
    const float* fcb  = (const float*)d_in[10];

    unsigned short* Bh = (unsigned short*)d_ws;
    unsigned short* Bl = Bh + NSUP * KP;

    prep_kernel<<<1, 256, 0, stream>>>(sidx, emb, Bh, Bl);
    main_kernel<<<512, 512, 0, stream>>>(tokens, emb, Bh, Bl,
                                         c1w, c1b, c2w, c2b,
                                         f2w, f2b, fcw, fcb, (float*)d_out);
}

// Round 2
// 119.742 us; speedup vs baseline: 1.4337x; 1.4337x over previous
//
#include <hip/hip_runtime.h>
#include <stdint.h>

#define VOCAB   100000
#define DIM     300
#define NBATCH  4096
#define RTOK    32
#define NSUP    64      // N*S = 2*32 support cols
#define KP      320     // K padded to 10*32
#define NKS     10      // K steps of 32
#define ASTRIDE 328     // LDS row stride (ushort) for A tiles (16B-aligned rows)
#define SMST    65      // LDS row stride (float) for sm tile

typedef float f32x4 __attribute__((ext_vector_type(4)));
typedef short s16x8 __attribute__((ext_vector_type(8)));

static __device__ __forceinline__ unsigned short f2bf(float x) {
    unsigned u = __builtin_bit_cast(unsigned, x);
    unsigned r = (u + 0x7FFFu + ((u >> 16) & 1u)) >> 16;
    return (unsigned short)r;
}
static __device__ __forceinline__ float bf2f(unsigned short h) {
    return __builtin_bit_cast(float, (unsigned)h << 16);
}

// ---------------- kernel 1: normalize support vectors -> bf16 hi/lo [64][320]
__global__ __launch_bounds__(256) void prep_kernel(
    const int* __restrict__ sidx, const float* __restrict__ emb,
    unsigned short* __restrict__ Bh, unsigned short* __restrict__ Bl) {
    const int w = threadIdx.x >> 6, l = threadIdx.x & 63;
    for (int rr = 0; rr < 16; ++rr) {
        const int j = w * 16 + rr;
        const size_t tok = (size_t)sidx[j];
        const float* src = emb + tok * DIM;
        float e[5];
        #pragma unroll
        for (int c = 0; c < 5; ++c) {
            const int k = c * 64 + l;
            e[c] = (k < DIM) ? src[k] : 0.f;
        }
        float s = e[0]*e[0] + e[1]*e[1] + e[2]*e[2] + e[3]*e[3] + e[4]*e[4];
        #pragma unroll
        for (int m = 32; m >= 1; m >>= 1) s += __shfl_xor(s, m);
        const float rn = 1.f / fmaxf(sqrtf(s), 1e-8f);
        #pragma unroll
        for (int c = 0; c < 5; ++c) {
            const int k = c * 64 + l;                 // always < 320
            const float v = (k < DIM) ? e[c] * rn : 0.f;
            const unsigned short h = f2bf(v);
            Bh[j * KP + k] = h;
            Bl[j * KP + k] = f2bf(v - bf2f(h));
        }
    }
}

// ---------------- kernel 2: fused gather+normalize+GEMM(split-bf16 MFMA)+tail
// one batch per block; 8 waves
__global__ __launch_bounds__(512, 6) void main_kernel(
    const int* __restrict__ tokens, const float* __restrict__ emb,
    const unsigned short* __restrict__ Bh, const unsigned short* __restrict__ Bl,
    const float* __restrict__ c1w, const float* __restrict__ c1b,
    const float* __restrict__ c2w, const float* __restrict__ c2b,
    const float* __restrict__ f2w, const float* __restrict__ f2b,
    const float* __restrict__ fcw, const float* __restrict__ fcb,
    float* __restrict__ out) {

    __shared__ __attribute__((aligned(16))) unsigned short Ah[32 * ASTRIDE];
    __shared__ __attribute__((aligned(16))) unsigned short Al[32 * ASTRIDE];
    __shared__ float smls[32 * SMST];
    __shared__ float pl1[2 * 16 * 16];
    __shared__ float scr[4];

    const int tid = threadIdx.x;
    const int w = tid >> 6, l = tid & 63;
    const int batch = blockIdx.x;

    // ---- gather + normalize + bf16 hi/lo into LDS (wave w: rows 4w..4w+3)
    #pragma unroll
    for (int rr = 0; rr < 4; ++rr) {
        const int row = w * 4 + rr;
        const size_t tok = (size_t)tokens[batch * RTOK + row];
        const float* src = emb + tok * DIM;
        float e[5];
        #pragma unroll
        for (int c = 0; c < 5; ++c) {
            const int k = c * 64 + l;
            e[c] = (k < DIM) ? src[k] : 0.f;
        }
        float s = e[0]*e[0] + e[1]*e[1] + e[2]*e[2] + e[3]*e[3] + e[4]*e[4];
        #pragma unroll
        for (int m = 32; m >= 1; m >>= 1) s += __shfl_xor(s, m);
        const float rn = 1.f / fmaxf(sqrtf(s), 1e-8f);
        #pragma unroll
        for (int c = 0; c < 5; ++c) {
            const int k = c * 64 + l;             // covers 0..319 incl. zero pad
            const float v = (k < DIM) ? e[c] * rn : 0.f;
            const unsigned short h = f2bf(v);
            Ah[row * ASTRIDE + k] = h;
            Al[row * ASTRIDE + k] = f2bf(v - bf2f(h));
        }
    }
    __syncthreads();

    // ---- MFMA: wave w -> rows (w>>2)*16..+15, cols (w&3)*16..+15
    // B fragments streamed from global (L2-hot, 80 KB working set)
    const int cb = (w & 3) * 16;
    {
        const int rb = (w >> 2) * 16;
        const int abase = (rb + (l & 15)) * ASTRIDE + (l >> 4) * 8;
        const int boff  = (cb + (l & 15)) * KP + (l >> 4) * 8;
        f32x4 a0 = {0,0,0,0}, a1 = {0,0,0,0}, a2 = {0,0,0,0};
        #pragma unroll
        for (int t = 0; t < NKS; ++t) {
            const s16x8 bh = *(const s16x8*)(Bh + boff + t * 32);
            const s16x8 bl = *(const s16x8*)(Bl + boff + t * 32);
            const s16x8 ah = *(const s16x8*)(Ah + abase + t * 32);
            const s16x8 al = *(const s16x8*)(Al + abase + t * 32);
            a0 = __builtin_amdgcn_mfma_f32_16x16x32_bf16(ah, bh, a0, 0, 0, 0);
            a1 = __builtin_amdgcn_mfma_f32_16x16x32_bf16(ah, bl, a1, 0, 0, 0);
            a2 = __builtin_amdgcn_mfma_f32_16x16x32_bf16(al, bh, a2, 0, 0, 0);
        }
        #pragma unroll
        for (int q = 0; q < 4; ++q) {
            const int row = rb + (l >> 4) * 4 + q;
            smls[row * SMST + cb + (l & 15)] = a0[q] + a1[q] + a2[q];
        }
    }
    __syncthreads();

    // ---- waves 0-1: softmax-pool per channel (no max needed: |sm| <= 1)
    if (w < 2) {
        const int ch = w;
        const float* base = &smls[(l & 31) * SMST + ch * 32 + (l >> 5) * 16];
        float se = 0.f, sv = 0.f;
        #pragma unroll
        for (int j = 0; j < 16; ++j) {
            const float v = base[j];
            const float e = __expf(v);
            se += e; sv += e * v;
        }
        #pragma unroll
        for (int k = 32; k >= 1; k >>= 1) { se += __shfl_xor(se, k); sv += __shfl_xor(sv, k); }
        if (l == 0) scr[ch] = sv / se;    // pooled value for this channel
    }

    // ---- all threads: conv1 per-ic partials (gate applied later)
    const int oc = tid >> 8, ii = (tid >> 4) & 15, jj = tid & 15;
    float pc[2][4] = {{0,0,0,0},{0,0,0,0}};
    #pragma unroll
    for (int ic = 0; ic < 2; ++ic) {
        float patch[4][4];
        #pragma unroll
        for (int a = 0; a < 4; ++a) {
            const int xx = 2 * jj - 1 + a;
            #pragma unroll
            for (int b = 0; b < 4; ++b) {
                const int yy = 2 * ii - 1 + b;
                patch[a][b] = (xx >= 0 && xx < 32 && yy >= 0 && yy < 32)
                            ? smls[xx * SMST + ic * 32 + yy] : 0.f;
            }
        }
        #pragma unroll
        for (int py = 0; py < 2; ++py)
        #pragma unroll
        for (int px = 0; px < 2; ++px)
        #pragma unroll
        for (int dy = 0; dy < 3; ++dy)
        #pragma unroll
        for (int dx = 0; dx < 3; ++dx)
            pc[ic][py * 2 + px] += c1w[(oc * 2 + ic) * 9 + dy * 3 + dx] *
                                   patch[px + dx][py + dy];
    }
    __syncthreads();

    // ---- gate + relu + maxpool -> pl1
    {
        const float p0 = scr[0], p1 = scr[1];
        const float g0 = 1.f / (1.f + __expf(-(f2w[0] * p0 + f2w[1] * p1 + f2b[0])));
        const float g1 = 1.f / (1.f + __expf(-(f2w[2] * p0 + f2w[3] * p1 + f2b[1])));
        const float bias = c1b[oc];
        float mx = 0.f;   // relu'd values are >= 0
        #pragma unroll
        for (int pos = 0; pos < 4; ++pos) {
            const float acc = bias + g0 * pc[0][pos] + g1 * pc[1][pos];
            mx = fmaxf(mx, acc);
        }
        pl1[tid] = mx;    // tid == oc*256 + ii*16 + jj  ([oc][y=s][x=r])
    }
    __syncthreads();

    // ---- wave 0: conv2(2x2,pad1)+relu+avgpool2 -> [2][8][8] + fc -> out
    if (w == 0) {
        float c0 = 0.f, c1 = 0.f;
        #pragma unroll
        for (int h = 0; h < 2; ++h) {
            const int o = h * 64 + l;             // flat output idx 0..127
            const int oc2 = o >> 6, ii2 = (o >> 3) & 7, jj2 = o & 7;
            float sum = 0.f;
            #pragma unroll
            for (int py = 0; py < 2; ++py)
            #pragma unroll
            for (int px = 0; px < 2; ++px) {
                const int y = 2 * ii2 + py, x = 2 * jj2 + px;
                float acc = c2b[oc2];
                #pragma unroll
                for (int ic = 0; ic < 2; ++ic)
                #pragma unroll
                for (int dy = 0; dy < 2; ++dy) {
                    const int yy = y - 1 + dy;
                    if (yy < 0 || yy > 15) continue;
                    #pragma unroll
                    for (int dx = 0; dx < 2; ++dx) {
                        const int xx = x - 1 + dx;
                        if (xx < 0 || xx > 15) continue;
                        acc += c2w[((oc2 * 2 + ic) * 2 + dy) * 2 + dx] *
                               pl1[ic * 256 + yy * 16 + xx];
                    }
                }
                sum += fmaxf(acc, 0.f);
            }
            const float val = 0.25f * sum;
            c0 += val * fcw[o];
            c1 += val * fcw[128 + o];
        }
        #pragma unroll
        for (int k = 32; k >= 1; k >>= 1) { c0 += __shfl_xor(c0, k); c1 += __shfl_xor(c1, k); }
        if (l == 0) {
            out[batch * 2 + 0] = fcb[0] + c0;
            out[batch * 2 + 1] = fcb[1] + c1;
        }
    }
}

extern "C" void kernel_launch(void* const* d_in, const int* in_sizes, int n_in,
                              void* d_out, int out_size, void* d_ws, size_t ws_size,
                              hipStream_t stream) {
    const int* tokens = (const int*)d_in[0];
    const int* sidx   = (const int*)d_in[1];
    const float* emb  = (const float*)d_in[2];
    const float* c1w  = (const float*)d_in[3];
    const float* c1b  = (const float*)d_in[4];
    const float* c2w  = (const float*)d_in[5];
    const float* c2b  = (const float*)d_in[6];
    const float* f2w  = (const float*)d_in[7];
    const float* f2b  = (const float*)d_in[8];
    const float* fcw  = (const float*)d_in[9];
    const float* fcb  = (const float*)d_in[10];

    unsigned short* Bh = (unsigned short*)d_ws;
    unsigned short* Bl = Bh + NSUP * KP;

    prep_kernel<<<1, 256, 0, stream>>>(sidx, emb, Bh, Bl);
    main_kernel<<<NBATCH, 512, 0, stream>>>(tokens, emb, Bh, Bl,
                                            c1w, c1b, c2w, c2b,
                                            f2w, f2b, fcw, fcb, (float*)d_out);
}

// Round 3
// 100.530 us; speedup vs baseline: 1.7077x; 1.1911x over previous
//
#include <hip/hip_runtime.h>
#include <stdint.h>

#define DIM     300
#define NBATCH  4096
#define RTOK    32
#define NSUP    64      // N*S = 2*32 support cols
#define KP      320     // K padded to 10*32
#define NKS     10      // K steps of 32
#define ASTRIDE 328     // LDS row stride (ushort) for A tiles (8B-aligned rows, bank-staggered)
#define SMST    82      // padded sm tile x-stride (floats); 2*82%32=4 -> 2-way banks
#define SMY     36      // per-channel y extent (34 used + 2 pad, even for b64 align)

typedef float f32x4 __attribute__((ext_vector_type(4)));
typedef short s16x8 __attribute__((ext_vector_type(8)));

static __device__ __forceinline__ unsigned bc(float x) { return __builtin_bit_cast(unsigned, x); }
static __device__ __forceinline__ float asf(unsigned u) { return __builtin_bit_cast(float, u); }
// pack [a.hi16 : b.hi16] in one v_perm_b32
static __device__ __forceinline__ unsigned perm_hi(unsigned a, unsigned b) {
    return __builtin_amdgcn_perm(a, b, 0x07060302u);
}
static __device__ __forceinline__ unsigned short f2bf(float x) {   // RNE (prep only)
    unsigned u = bc(x);
    return (unsigned short)((u + 0x7FFFu + ((u >> 16) & 1u)) >> 16);
}
static __device__ __forceinline__ float bf2f(unsigned short h) { return asf((unsigned)h << 16); }

// ---------------- kernel 1: normalize support vectors -> bf16 hi/lo [64][320]
__global__ __launch_bounds__(64) void prep_kernel(
    const int* __restrict__ sidx, const float* __restrict__ emb,
    unsigned short* __restrict__ Bh, unsigned short* __restrict__ Bl) {
    const int j = blockIdx.x, l = threadIdx.x;
    const size_t tok = (size_t)sidx[j];
    const float* src = emb + tok * DIM;
    float e[5];
    #pragma unroll
    for (int c = 0; c < 5; ++c) {
        const int k = c * 64 + l;
        e[c] = (k < DIM) ? src[k] : 0.f;
    }
    float s = e[0]*e[0] + e[1]*e[1] + e[2]*e[2] + e[3]*e[3] + e[4]*e[4];
    #pragma unroll
    for (int m = 32; m >= 1; m >>= 1) s += __shfl_xor(s, m);
    const float rn = 1.f / fmaxf(sqrtf(s), 1e-8f);
    #pragma unroll
    for (int c = 0; c < 5; ++c) {
        const int k = c * 64 + l;                 // always < 320
        const float v = (k < DIM) ? e[c] * rn : 0.f;
        const unsigned short h = f2bf(v);
        Bh[j * KP + k] = h;
        Bl[j * KP + k] = f2bf(v - bf2f(h));
    }
}

// ---------------- kernel 2: fused gather + split-bf16 MFMA GEMM (+Gram norms) + tail
__global__ __launch_bounds__(512, 6) void main_kernel(
    const int* __restrict__ tokens, const float* __restrict__ emb,
    const unsigned short* __restrict__ Bh, const unsigned short* __restrict__ Bl,
    const float* __restrict__ c1w, const float* __restrict__ c1b,
    const float* __restrict__ c2w, const float* __restrict__ c2b,
    const float* __restrict__ f2w, const float* __restrict__ f2b,
    const float* __restrict__ fcw, const float* __restrict__ fcb,
    float* __restrict__ out) {

    __shared__ __attribute__((aligned(16))) unsigned short Ah[32 * ASTRIDE];
    __shared__ __attribute__((aligned(16))) unsigned short Al[32 * ASTRIDE];
    __shared__ __attribute__((aligned(16))) float smP[34 * SMST];  // [xp=r+1][ch][yp=s+1], zero-bordered
    __shared__ __attribute__((aligned(16))) float norms[32];
    __shared__ float scr[2];
    float* pl1P = (float*)Ah;   // overlay: [2][17][18] zero-bordered pool1, used after GEMM

    const int tid = threadIdx.x;
    const int w = tid >> 6, l = tid & 63;
    const int batch = blockIdx.x;

    // ---- P0: clear smP (697 float4 chunks) + gather 4 rows/wave
    {
        const f32x4 z = {0.f, 0.f, 0.f, 0.f};
        ((f32x4*)smP)[tid] = z;
        if (tid < 697 - 512) ((f32x4*)smP)[512 + tid] = z;
    }
    {
        const int row0 = w * 4;
        const bool tl = (l < DIM - 256);          // tail lanes 0..43
        float4 e4[4]; float et[4];
        #pragma unroll
        for (int rr = 0; rr < 4; ++rr) {
            const size_t tok = (size_t)tokens[batch * RTOK + row0 + rr];
            const float* src = emb + tok * DIM;
            e4[rr] = *(const float4*)(src + 4 * l);
            et[rr] = tl ? src[256 + l] : 0.f;
        }
        #pragma unroll
        for (int rr = 0; rr < 4; ++rr) {
            const int row = row0 + rr;
            // round-half-up hi (lo captures the rounding error exactly)
            const unsigned u0 = bc(e4[rr].x) + 0x8000u, u1 = bc(e4[rr].y) + 0x8000u;
            const unsigned u2 = bc(e4[rr].z) + 0x8000u, u3 = bc(e4[rr].w) + 0x8000u;
            const float r0 = e4[rr].x - asf(u0 & 0xffff0000u);
            const float r1 = e4[rr].y - asf(u1 & 0xffff0000u);
            const float r2 = e4[rr].z - asf(u2 & 0xffff0000u);
            const float r3 = e4[rr].w - asf(u3 & 0xffff0000u);
            const unsigned h01 = perm_hi(u1, u0), h23 = perm_hi(u3, u2);
            const unsigned l01 = perm_hi(bc(r1) + 0x8000u, bc(r0) + 0x8000u);
            const unsigned l23 = perm_hi(bc(r3) + 0x8000u, bc(r2) + 0x8000u);
            *(uint2*)(&Ah[row * ASTRIDE + 4 * l]) = uint2{h01, h23};
            *(uint2*)(&Al[row * ASTRIDE + 4 * l]) = uint2{l01, l23};
            // tail elem k=256+l (lanes >=44 store zeros -> K-padding 300..319)
            const unsigned ut = bc(et[rr]) + 0x8000u;
            const float rt = et[rr] - asf(ut & 0xffff0000u);
            Ah[row * ASTRIDE + 256 + l] = (unsigned short)(ut >> 16);
            Al[row * ASTRIDE + 256 + l] = (unsigned short)((bc(rt) + 0x8000u) >> 16);
        }
    }
    __syncthreads();   // BAR1

    // ---- P1: MFMA GEMM + Gram-diag row norms; wave w -> rows (w>>2)*16, cols (w&3)*16
    const int cb = (w & 3) * 16, rb = (w >> 2) * 16;
    const int c = l & 15;
    {
        const int abase = (rb + c) * ASTRIDE + (l >> 4) * 8;
        const int boff  = (cb + c) * KP + (l >> 4) * 8;
        f32x4 a0 = {0,0,0,0}, a1 = {0,0,0,0}, a2 = {0,0,0,0};
        f32x4 gv = {0,0,0,0}, g2 = {0,0,0,0};
        #pragma unroll
        for (int t = 0; t < NKS; ++t) {
            const s16x8 bh = *(const s16x8*)(Bh + boff + t * 32);
            const s16x8 bl = *(const s16x8*)(Bl + boff + t * 32);
            const s16x8 ah = *(const s16x8*)(Ah + abase + t * 32);
            const s16x8 al = *(const s16x8*)(Al + abase + t * 32);
            a0 = __builtin_amdgcn_mfma_f32_16x16x32_bf16(ah, bh, a0, 0, 0, 0);
            a1 = __builtin_amdgcn_mfma_f32_16x16x32_bf16(ah, bl, a1, 0, 0, 0);
            a2 = __builtin_amdgcn_mfma_f32_16x16x32_bf16(al, bh, a2, 0, 0, 0);
            gv = __builtin_amdgcn_mfma_f32_16x16x32_bf16(ah, ah, gv, 0, 0, 0);
            g2 = __builtin_amdgcn_mfma_f32_16x16x32_bf16(ah, al, g2, 0, 0, 0);
        }
        // diagonal lanes write |x_row|^2 (race across twin waves: identical values)
        if ((l >> 4) == (c >> 2)) {
            const int q = c & 3;
            const float d1 = (q == 0) ? gv[0] : (q == 1) ? gv[1] : (q == 2) ? gv[2] : gv[3];
            const float d2 = (q == 0) ? g2[0] : (q == 1) ? g2[1] : (q == 2) ? g2[2] : g2[3];
            norms[rb + c] = d1 + 2.f * d2;
        }
        asm volatile("s_waitcnt lgkmcnt(0)" ::: "memory");   // intra-wave LDS write->read
        const f32x4 n4 = *(const f32x4*)&norms[rb + (l >> 4) * 4];
        const int col = cb + c, ch = col >> 5, s = col & 31;
        #pragma unroll
        for (int q = 0; q < 4; ++q) {
            const float rn = __builtin_amdgcn_rcpf(
                fmaxf(__builtin_amdgcn_sqrtf(n4[q]), 1e-8f));
            const int row = rb + (l >> 4) * 4 + q;
            smP[(row + 1) * SMST + ch * SMY + (s + 1)] = (a0[q] + a1[q] + a2[q]) * rn;
        }
    }
    __syncthreads();   // BAR2

    // ---- P2: softmax-pool (waves 0-1) + pl1 border zero + conv1 partials (all)
    if (w < 2) {        // channel w; lane covers row r = l&31, s-half l>>5
        const int r = l & 31, hf = l >> 5;
        const float* bp = &smP[(r + 1) * SMST + w * SMY + 1 + hf * 16];
        float se = 0.f, sv = 0.f;
        #pragma unroll
        for (int j = 0; j < 16; ++j) {
            const float v = bp[j];
            const float e = __expf(v);       // |v| <= 1: no max-shift needed
            se += e; sv = fmaf(e, v, sv);
        }
        #pragma unroll
        for (int m = 32; m >= 1; m >>= 1) { se += __shfl_xor(se, m); sv += __shfl_xor(sv, m); }
        if (l == 0) scr[w] = sv / se;
    }
    if (tid >= 446) {   // zero pl1P borders: yp=0 row (17) + xp=0 col (16), x2 channels
        const int z = tid - 446;
        const int ic = z / 33, rm = z % 33;
        pl1P[ic * 306 + (rm < 17 ? rm : (rm - 16) * 18)] = 0.f;
    }
    const int oc = tid >> 8, ii = (tid >> 4) & 15, jj = tid & 15;
    float pc[2][4] = {{0,0,0,0},{0,0,0,0}};
    #pragma unroll
    for (int ic = 0; ic < 2; ++ic) {
        float p[4][4];
        #pragma unroll
        for (int a = 0; a < 4; ++a) {        // xp = 2jj+a, yp base 2ii (both even: b64 ok)
            const int off = (2 * jj + a) * SMST + ic * SMY + 2 * ii;
            const float2 v01 = *(const float2*)&smP[off];
            const float2 v23 = *(const float2*)&smP[off + 2];
            p[a][0] = v01.x; p[a][1] = v01.y; p[a][2] = v23.x; p[a][3] = v23.y;
        }
        #pragma unroll
        for (int py = 0; py < 2; ++py)
        #pragma unroll
        for (int px = 0; px < 2; ++px)
        #pragma unroll
        for (int dy = 0; dy < 3; ++dy)
        #pragma unroll
        for (int dx = 0; dx < 3; ++dx)
            pc[ic][py * 2 + px] += c1w[(oc * 2 + ic) * 9 + dy * 3 + dx] * p[px + dx][py + dy];
    }
    __syncthreads();   // BAR3

    // ---- P3: gate + relu + maxpool -> pl1P
    {
        const float p0s = scr[0], p1s = scr[1];
        const float gg0 = 1.f / (1.f + __expf(-(f2w[0] * p0s + f2w[1] * p1s + f2b[0])));
        const float gg1 = 1.f / (1.f + __expf(-(f2w[2] * p0s + f2w[3] * p1s + f2b[1])));
        const float bias = c1b[oc];
        float mx = 0.f;    // relu folded: start at 0
        #pragma unroll
        for (int i = 0; i < 4; ++i)
            mx = fmaxf(mx, bias + gg0 * pc[0][i] + gg1 * pc[1][i]);
        pl1P[oc * 306 + (ii + 1) * 18 + (jj + 1)] = mx;
    }
    __syncthreads();   // BAR4

    // ---- P4: wave 0: conv2(2x2,pad1)+relu+avgpool2 + fc -> out
    if (w == 0) {
        float o0 = 0.f, o1 = 0.f;
        #pragma unroll
        for (int h = 0; h < 2; ++h) {
            const int o = h * 64 + l, oc2 = o >> 6, ii2 = (o >> 3) & 7, jj2 = o & 7;
            float sum = 0.f;
            #pragma unroll
            for (int py = 0; py < 2; ++py)
            #pragma unroll
            for (int px = 0; px < 2; ++px) {
                const int y = 2 * ii2 + py, x = 2 * jj2 + px;
                float acc = c2b[oc2];
                #pragma unroll
                for (int ic = 0; ic < 2; ++ic)
                #pragma unroll
                for (int dy = 0; dy < 2; ++dy)
                #pragma unroll
                for (int dx = 0; dx < 2; ++dx)
                    acc += c2w[((oc2 * 2 + ic) * 2 + dy) * 2 + dx] *
                           pl1P[ic * 306 + (y + dy) * 18 + (x + dx)];
                sum += fmaxf(acc, 0.f);
            }
            const float val = 0.25f * sum;
            o0 = fmaf(val, fcw[o], o0);
            o1 = fmaf(val, fcw[128 + o], o1);
        }
        #pragma unroll
        for (int m = 32; m >= 1; m >>= 1) { o0 += __shfl_xor(o0, m); o1 += __shfl_xor(o1, m); }
        if (l == 0) {
            out[batch * 2 + 0] = fcb[0] + o0;
            out[batch * 2 + 1] = fcb[1] + o1;
        }
    }
}

extern "C" void kernel_launch(void* const* d_in, const int* in_sizes, int n_in,
                              void* d_out, int out_size, void* d_ws, size_t ws_size,
                              hipStream_t stream) {
    const int* tokens = (const int*)d_in[0];
    const int* sidx   = (const int*)d_in[1];
    const float* emb  = (const float*)d_in[2];
    const float* c1w  = (const float*)d_in[3];
    const float* c1b  = (const float*)d_in[4];
    const float* c2w  = (const float*)d_in[5];
    const float* c2b  = (const float*)d_in[6];
    const float* f2w  = (const float*)d_in[7];
    const float* f2b  = (const float*)d_in[8];
    const float* fcw  = (const float*)d_in[9];
    const float* fcb  = (const float*)d_in[10];

    unsigned short* Bh = (unsigned short*)d_ws;
    unsigned short* Bl = Bh + NSUP * KP;

    prep_kernel<<<NSUP, 64, 0, stream>>>(sidx, emb, Bh, Bl);
    main_kernel<<<NBATCH, 512, 0, stream>>>(tokens, emb, Bh, Bl,
                                            c1w, c1b, c2w, c2b,
                                            f2w, f2b, fcw, fcb, (float*)d_out);
}